// Round 1
// baseline (639.898 us; speedup 1.0000x reference)
//
#include <hip/hip_runtime.h>
#include <math.h>

// Problem constants (fixed by the reference): x,y are [4, 64, 64, 64] fp32.
constexpr int B_   = 4;
constexpr int C_   = 64;
constexpr int HW   = 64 * 64;      // N = 4096
constexpr int ROWS = B_ * HW;      // 16384 points per tensor

constexpr float SIGMA    = 0.1f;
constexpr float EPS_MIN  = 1e-5f;
constexpr float EPS_NORM = 1e-12f;

constexpr int TN = 64;             // n-rows per block (one wave, 1 row/lane)
constexpr int MC = 16;             // m-chunks per row
constexpr int MCHUNK = HW / MC;    // 256 m per block

// ---------------------------------------------------------------------------
// Init accumulators (ws is re-poisoned to 0xAA before every timed launch).
__global__ __launch_bounds__(256) void init_kernel(unsigned* __restrict__ dmin_u,
                                                   float* __restrict__ S) {
    int i = blockIdx.x * blockDim.x + threadIdx.x;
    if (i < ROWS) {
        dmin_u[i] = 0x7F800000u;   // +inf bit pattern
        S[i] = 0.0f;
    }
}

// ---------------------------------------------------------------------------
// Normalize along channel dim; write transposed [B, N, C] layout.
// Reads are coalesced across lanes (consecutive n for fixed c).
__global__ __launch_bounds__(256) void nrm_kernel(const float* __restrict__ x,
                                                  const float* __restrict__ y,
                                                  float* __restrict__ xn,
                                                  float* __restrict__ yn) {
    int p = blockIdx.x * blockDim.x + threadIdx.x;   // 0 .. 2*ROWS-1
    const float* src;
    float* dst;
    int q;
    if (p < ROWS) { src = x; dst = xn; q = p; }
    else          { src = y; dst = yn; q = p - ROWS; }
    int b = q >> 12;          // / 4096
    int n = q & (HW - 1);
    const float* base = src + ((size_t)b * C_) * HW + n;
    float v[C_];
    float ss = 0.0f;
#pragma unroll
    for (int c = 0; c < C_; ++c) {
        v[c] = base[(size_t)c * HW];
        ss = fmaf(v[c], v[c], ss);
    }
    float scale = 1.0f / fmaxf(sqrtf(ss), EPS_NORM);
    float4* o = (float4*)(dst + (size_t)q * C_);
#pragma unroll
    for (int c = 0; c < C_ / 4; ++c) {
        o[c] = make_float4(v[4*c+0]*scale, v[4*c+1]*scale,
                           v[4*c+2]*scale, v[4*c+3]*scale);
    }
}

// ---------------------------------------------------------------------------
// Pass A: per-row min distance.  Block = 1 wave, lane t owns row n = nt*64+t,
// scans an m-chunk of 256 columns.  y-row loads are wave-uniform (scalarize).
__global__ __launch_bounds__(64) void dmin_kernel(const float* __restrict__ xn,
                                                  const float* __restrict__ yn,
                                                  unsigned* __restrict__ dmin_u) {
    int mc = blockIdx.x;
    int nt = blockIdx.y;
    int b  = blockIdx.z;
    int n  = nt * TN + threadIdx.x;
    int row = b * HW + n;

    const float* xr = xn + (size_t)row * C_;
    float xv[C_];
#pragma unroll
    for (int c = 0; c < C_; ++c) xv[c] = xr[c];

    const float* yb = yn + ((size_t)b * HW + (size_t)mc * MCHUNK) * C_;
    float mn = INFINITY;
    for (int m = 0; m < MCHUNK; ++m) {
        const float* yr = yb + (size_t)m * C_;
        float dot = 0.0f;
#pragma unroll
        for (int c = 0; c < C_; ++c) dot = fmaf(xv[c], yr[c], dot);
        float d2 = fmaxf(2.0f - 2.0f * dot, 0.0f);
        mn = fminf(mn, sqrtf(d2));
    }
    atomicMin(&dmin_u[row], __float_as_uint(mn));  // valid: all values >= 0
}

// ---------------------------------------------------------------------------
// Pass B: S_row = sum_m exp((dmin - d_m) / (sigma*(dmin+eps))).
__global__ __launch_bounds__(64) void sum_kernel(const float* __restrict__ xn,
                                                 const float* __restrict__ yn,
                                                 const unsigned* __restrict__ dmin_u,
                                                 float* __restrict__ S) {
    int mc = blockIdx.x;
    int nt = blockIdx.y;
    int b  = blockIdx.z;
    int n  = nt * TN + threadIdx.x;
    int row = b * HW + n;

    const float* xr = xn + (size_t)row * C_;
    float xv[C_];
#pragma unroll
    for (int c = 0; c < C_; ++c) xv[c] = xr[c];

    float dmin = __uint_as_float(dmin_u[row]);
    float kk = 1.0f / (SIGMA * (dmin + EPS_MIN));

    const float* yb = yn + ((size_t)b * HW + (size_t)mc * MCHUNK) * C_;
    float acc = 0.0f;
    for (int m = 0; m < MCHUNK; ++m) {
        const float* yr = yb + (size_t)m * C_;
        float dot = 0.0f;
#pragma unroll
        for (int c = 0; c < C_; ++c) dot = fmaf(xv[c], yr[c], dot);
        float d2 = fmaxf(2.0f - 2.0f * dot, 0.0f);
        float d  = sqrtf(d2);
        acc += expf((dmin - d) * kk);   // arg <= 0, no overflow
    }
    atomicAdd(&S[row], acc);
}

// ---------------------------------------------------------------------------
// Final: loss = -log( mean(1/S + EPS_MIN) ).
__global__ __launch_bounds__(256) void final_kernel(const float* __restrict__ S,
                                                    float* __restrict__ out) {
    float acc = 0.0f;
    for (int i = threadIdx.x; i < ROWS; i += 256)
        acc += 1.0f / S[i] + EPS_MIN;
    // wave reduce (64 lanes)
#pragma unroll
    for (int off = 32; off > 0; off >>= 1)
        acc += __shfl_down(acc, off);
    __shared__ float part[4];
    if ((threadIdx.x & 63) == 0) part[threadIdx.x >> 6] = acc;
    __syncthreads();
    if (threadIdx.x == 0) {
        float t = part[0] + part[1] + part[2] + part[3];
        out[0] = -logf(t / (float)ROWS);
    }
}

// ---------------------------------------------------------------------------
extern "C" void kernel_launch(void* const* d_in, const int* in_sizes, int n_in,
                              void* d_out, int out_size, void* d_ws, size_t ws_size,
                              hipStream_t stream) {
    const float* x = (const float*)d_in[0];
    const float* y = (const float*)d_in[1];
    float* out = (float*)d_out;

    char* ws = (char*)d_ws;
    size_t nrm_bytes = (size_t)ROWS * C_ * sizeof(float);   // 4 MB each
    float*    xn     = (float*)(ws);
    float*    yn     = (float*)(ws + nrm_bytes);
    unsigned* dmin_u = (unsigned*)(ws + 2 * nrm_bytes);
    float*    S      = (float*)(ws + 2 * nrm_bytes + (size_t)ROWS * sizeof(unsigned));

    hipLaunchKernelGGL(init_kernel, dim3((ROWS + 255) / 256), dim3(256), 0, stream,
                       dmin_u, S);
    hipLaunchKernelGGL(nrm_kernel, dim3(2 * ROWS / 256), dim3(256), 0, stream,
                       x, y, xn, yn);
    dim3 grid(MC, HW / TN, B_);
    hipLaunchKernelGGL(dmin_kernel, grid, dim3(64), 0, stream, xn, yn, dmin_u);
    hipLaunchKernelGGL(sum_kernel,  grid, dim3(64), 0, stream, xn, yn, dmin_u, S);
    hipLaunchKernelGGL(final_kernel, dim3(1), dim3(256), 0, stream, S, out);
}

// Round 2
// 209.733 us; speedup vs baseline: 3.0510x; 3.0510x over previous
//
#include <hip/hip_runtime.h>
#include <math.h>

// Problem constants (fixed by the reference): x,y are [4, 64, 64, 64] fp32.
constexpr int B_   = 4;
constexpr int C_   = 64;
constexpr int HW   = 4096;         // N = 64*64
constexpr int ROWS = B_ * HW;      // 16384

constexpr float SIGMA    = 0.1f;
constexpr float EPS_MIN  = 1e-5f;
constexpr float EPS_NORM = 1e-12f;

// Each wave owns a 16-row strip x CCHUNK-col chunk of one batch's 4096x4096
// distance matrix; 8-way col split restores occupancy (32 waves/CU target).
constexpr int CCHUNK      = 512;
constexpr int NCHUNK      = HW / CCHUNK;            // 8
constexpr int TASKS_PER_B = (HW / 16) * NCHUNK;     // 2048
constexpr int NBLOCKS     = B_ * TASKS_PER_B / 4;   // 2048 blocks of 4 waves

using short8  = __attribute__((ext_vector_type(8))) short;   // 8 bf16
using floatx4 = __attribute__((ext_vector_type(4))) float;

__device__ inline ushort f2bf(float f) {           // RNE float->bf16
    unsigned u = __float_as_uint(f);
    unsigned r = u + 0x7FFFu + ((u >> 16) & 1u);
    return (ushort)(r >> 16);
}

// ---------------------------------------------------------------------------
// Normalize along C, write bf16 [B][N][C] point-major; also init dmin/S
// (ws is re-poisoned to 0xAA before every timed launch).
__global__ __launch_bounds__(256) void nrm_kernel(const float* __restrict__ x,
                                                  const float* __restrict__ y,
                                                  ushort* __restrict__ xn,
                                                  ushort* __restrict__ yn,
                                                  unsigned* __restrict__ dmin_u,
                                                  float* __restrict__ S) {
    int p = blockIdx.x * 256 + threadIdx.x;        // 0 .. 2*ROWS-1
    if (p < ROWS) { dmin_u[p] = 0x7F800000u; S[p] = 0.0f; }   // +inf, 0
    const float* src; ushort* dst; int q;
    if (p < ROWS) { src = x; dst = xn; q = p; }
    else          { src = y; dst = yn; q = p - ROWS; }
    int b = q >> 12;
    int n = q & (HW - 1);
    const float* base = src + ((size_t)b * C_) * HW + n;  // coalesced over n
    float v[C_];
    float ss = 0.0f;
#pragma unroll
    for (int c = 0; c < C_; ++c) {
        v[c] = base[(size_t)c * HW];
        ss = fmaf(v[c], v[c], ss);
    }
    float scale = 1.0f / fmaxf(sqrtf(ss), EPS_NORM);
    short8* o = (short8*)(dst + (size_t)q * C_);
#pragma unroll
    for (int c8 = 0; c8 < C_ / 8; ++c8) {
        short8 pk;
#pragma unroll
        for (int j = 0; j < 8; ++j) pk[j] = (short)f2bf(v[c8 * 8 + j] * scale);
        o[c8] = pk;
    }
}

// ---------------------------------------------------------------------------
// PASS 0: dmin[row] = min_m d(row,m)   (tracks min d^2, one sqrt at end)
// PASS 1: S[row]   += sum_m exp((dmin - d) * kk),  kk = 1/(sigma*(dmin+eps))
// A/B frags both loaded identically from [point][k] bf16 arrays: any
// within-lane k-permutation cancels (m92 pattern). C/D: col=lane&15 (B point),
// row=(lane>>4)*4+reg (A point)  [m89/m91 verified].
template <int PASS>
__global__ __launch_bounds__(256) void gemm_pass(const ushort* __restrict__ xn,
                                                 const ushort* __restrict__ yn,
                                                 unsigned* __restrict__ dmin_u,
                                                 float* __restrict__ S) {
    int wid  = threadIdx.x >> 6;
    int lane = threadIdx.x & 63;
    int task = blockIdx.x * 4 + wid;
    int b     = task >> 11;          // / 2048
    int rem   = task & 2047;
    int strip = rem >> 3;            // 0..255  (16-row strip)
    int chunk = rem & 7;             // 0..7    (512-col chunk)
    int nbase = strip * 16;
    int cbase = chunk * CCHUNK;

    int lrow = lane & 15;
    int kblk = lane >> 4;

    const ushort* xb = xn + ((size_t)(b * HW + nbase)) * C_;
    const ushort* yb = yn + ((size_t)(b * HW + cbase)) * C_;

    short8 a0 = *(const short8*)(xb + lrow * C_ + kblk * 8);        // k 0..31
    short8 a1 = *(const short8*)(xb + lrow * C_ + 32 + kblk * 8);   // k 32..63

    int row0 = b * HW + nbase + kblk * 4;   // + r  (this lane's 4 output rows)

    float st[4];                    // PASS0: min d^2 ; PASS1: exp-sum
    float dmn[4], kk[4];
    if (PASS == 0) {
#pragma unroll
        for (int r = 0; r < 4; ++r) st[r] = INFINITY;
    } else {
#pragma unroll
        for (int r = 0; r < 4; ++r) {
            float dm = __uint_as_float(dmin_u[row0 + r]);
            dmn[r] = dm;
            kk[r]  = 1.0f / (SIGMA * (dm + EPS_MIN));
            st[r]  = 0.0f;
        }
    }

    for (int mt = 0; mt < CCHUNK / 16; ++mt) {
        const ushort* ybt = yb + (size_t)mt * 16 * C_;
        short8 b0 = *(const short8*)(ybt + lrow * C_ + kblk * 8);
        short8 b1 = *(const short8*)(ybt + lrow * C_ + 32 + kblk * 8);
        floatx4 acc = {0.0f, 0.0f, 0.0f, 0.0f};
        acc = __builtin_amdgcn_mfma_f32_16x16x32_bf16(a0, b0, acc, 0, 0, 0);
        acc = __builtin_amdgcn_mfma_f32_16x16x32_bf16(a1, b1, acc, 0, 0, 0);
#pragma unroll
        for (int r = 0; r < 4; ++r) {
            float d2 = fmaf(-2.0f, acc[r], 2.0f);   // ||xn||=||yn||=1
            if (PASS == 0) {
                st[r] = fminf(st[r], d2);
            } else {
                float d = sqrtf(fmaxf(d2, 0.0f));
                st[r] += __expf((dmn[r] - d) * kk[r]);   // arg <= ~0
            }
        }
    }

    // reduce across the 16 lanes of each row-group (cols live in lane&15)
#pragma unroll
    for (int off = 1; off < 16; off <<= 1) {
#pragma unroll
        for (int r = 0; r < 4; ++r) {
            float o = __shfl_xor(st[r], off);
            st[r] = (PASS == 0) ? fminf(st[r], o) : (st[r] + o);
        }
    }
    if (lrow == 0) {
#pragma unroll
        for (int r = 0; r < 4; ++r) {
            if (PASS == 0) {
                float d = sqrtf(fmaxf(st[r], 0.0f));
                atomicMin(&dmin_u[row0 + r], __float_as_uint(d)); // vals >= 0
            } else {
                atomicAdd(&S[row0 + r], st[r]);
            }
        }
    }
}

// ---------------------------------------------------------------------------
// loss = -log( mean(1/S + EPS_MIN) )
__global__ __launch_bounds__(256) void final_kernel(const float* __restrict__ S,
                                                    float* __restrict__ out) {
    float acc = 0.0f;
    for (int i = threadIdx.x; i < ROWS; i += 256)
        acc += 1.0f / S[i] + EPS_MIN;
#pragma unroll
    for (int off = 32; off > 0; off >>= 1)
        acc += __shfl_down(acc, off);
    __shared__ float part[4];
    if ((threadIdx.x & 63) == 0) part[threadIdx.x >> 6] = acc;
    __syncthreads();
    if (threadIdx.x == 0) {
        float t = part[0] + part[1] + part[2] + part[3];
        out[0] = -logf(t / (float)ROWS);
    }
}

// ---------------------------------------------------------------------------
extern "C" void kernel_launch(void* const* d_in, const int* in_sizes, int n_in,
                              void* d_out, int out_size, void* d_ws, size_t ws_size,
                              hipStream_t stream) {
    const float* x = (const float*)d_in[0];
    const float* y = (const float*)d_in[1];
    float* out = (float*)d_out;

    char* ws = (char*)d_ws;
    size_t nrm_bytes = (size_t)ROWS * C_ * sizeof(ushort);   // 2 MB each
    ushort*   xn     = (ushort*)(ws);
    ushort*   yn     = (ushort*)(ws + nrm_bytes);
    unsigned* dmin_u = (unsigned*)(ws + 2 * nrm_bytes);
    float*    S      = (float*)(ws + 2 * nrm_bytes + (size_t)ROWS * sizeof(unsigned));

    hipLaunchKernelGGL(nrm_kernel, dim3(2 * ROWS / 256), dim3(256), 0, stream,
                       x, y, xn, yn, dmin_u, S);
    hipLaunchKernelGGL(gemm_pass<0>, dim3(NBLOCKS), dim3(256), 0, stream,
                       xn, yn, dmin_u, S);
    hipLaunchKernelGGL(gemm_pass<1>, dim3(NBLOCKS), dim3(256), 0, stream,
                       xn, yn, dmin_u, S);
    hipLaunchKernelGGL(final_kernel, dim3(1), dim3(256), 0, stream, S, out);
}

// Round 3
// 123.128 us; speedup vs baseline: 5.1970x; 1.7034x over previous
//
#include <hip/hip_runtime.h>
#include <math.h>

// Problem constants (fixed by the reference): x,y are [4, 64, 64, 64] fp32.
constexpr int B_   = 4;
constexpr int C_   = 64;
constexpr int HW   = 4096;         // N = 64*64
constexpr int ROWS = B_ * HW;      // 16384

constexpr float SIGMA    = 0.1f;
constexpr float EPS_MIN  = 1e-5f;
constexpr float EPS_NORM = 1e-12f;

// Block geometry: 4 waves cover XR=64 x-rows (16 each), sharing a CC=512-col
// y-chunk staged through LDS in SR=64-row double-buffered stages.
constexpr int CC = 512;            // y-cols per block
constexpr int SR = 64;             // y-rows per LDS stage (8 KB)
constexpr int NS = CC / SR;        // 8 stages
constexpr int XR = 64;             // x-rows per block

using short8  = __attribute__((ext_vector_type(8))) short;   // 8 bf16
using floatx4 = __attribute__((ext_vector_type(4))) float;

__device__ inline ushort f2bf(float f) {           // RNE float->bf16
    unsigned u = __float_as_uint(f);
    unsigned r = u + 0x7FFFu + ((u >> 16) & 1u);
    return (ushort)(r >> 16);
}

// XOR swizzle for [row][128B] bf16 LDS tiles (G4): spreads the 16B slot
// across banks. Applied on BOTH write and read (involution).
__device__ inline int swz(int d) {                 // d = byte offset in stage
    int row = d >> 7;
    return (d & ~127) | ((d & 127) ^ ((row & 7) << 4));
}

// ---------------------------------------------------------------------------
// Normalize along C, write bf16 [B][N][C] point-major; also init dmin/S.
__global__ __launch_bounds__(256) void nrm_kernel(const float* __restrict__ x,
                                                  const float* __restrict__ y,
                                                  ushort* __restrict__ xn,
                                                  ushort* __restrict__ yn,
                                                  unsigned* __restrict__ dmin_u,
                                                  float* __restrict__ S) {
    int p = blockIdx.x * 256 + threadIdx.x;        // 0 .. 2*ROWS-1
    if (p < ROWS) { dmin_u[p] = 0x7F800000u; S[p] = 0.0f; }   // +inf, 0
    const float* src; ushort* dst; int q;
    if (p < ROWS) { src = x; dst = xn; q = p; }
    else          { src = y; dst = yn; q = p - ROWS; }
    int b = q >> 12;
    int n = q & (HW - 1);
    const float* base = src + ((size_t)b * C_) * HW + n;  // coalesced over n
    float v[C_];
    float ss = 0.0f;
#pragma unroll
    for (int c = 0; c < C_; ++c) {
        v[c] = base[(size_t)c * HW];
        ss = fmaf(v[c], v[c], ss);
    }
    float scale = 1.0f / fmaxf(sqrtf(ss), EPS_NORM);
    short8* o = (short8*)(dst + (size_t)q * C_);
#pragma unroll
    for (int c8 = 0; c8 < C_ / 8; ++c8) {
        short8 pk;
#pragma unroll
        for (int j = 0; j < 8; ++j) pk[j] = (short)f2bf(v[c8 * 8 + j] * scale);
        o[c8] = pk;
    }
}

// ---------------------------------------------------------------------------
// PASS 0: per-row max dot (min d is monotone in dot) -> atomicMin of d bits.
// PASS 1: S[row] += sum_m exp((dmin - d_m) * kk),  kk = 1/(sigma*(dmin+eps)).
// MFMA C/D: col=lane&15 (y point), row=(lane>>4)*4+reg (x point) [m89/m91].
// A and B frags both linear [point][k] (LDS swizzle undone on read) -> any
// within-lane k-permutation cancels between operands.
template <int PASS>
__global__ __launch_bounds__(256, 8) void gemm_pass(const ushort* __restrict__ xn,
                                                    const ushort* __restrict__ yn,
                                                    unsigned* __restrict__ dmin_u,
                                                    float* __restrict__ S) {
    __shared__ ushort lds[2][SR * C_];             // 2 x 8 KB

    int tid  = threadIdx.x;
    int wid  = tid >> 6;
    int lane = tid & 63;
    int lrow = lane & 15;
    int kblk = lane >> 4;

    int b     = blockIdx.z;
    int nbase = blockIdx.y * XR + wid * 16;
    int cbase = blockIdx.x * CC;

    const ushort* xb = xn + (size_t)(b * HW + nbase) * C_;
    const short8* yv = (const short8*)(yn + (size_t)(b * HW + cbase) * C_);

    short8 a0 = *(const short8*)(xb + lrow * C_ + kblk * 8);        // k 0..31
    short8 a1 = *(const short8*)(xb + lrow * C_ + 32 + kblk * 8);   // k 32..63

    int row0 = b * HW + nbase + kblk * 4;   // + r : this lane's 4 output rows

    // Per-thread staging slots: dest bytes tid*16 and tid*16+4096 of a stage.
    int w0 = swz(tid * 16) >> 1;            // ushort index, swizzled
    int w1 = swz(tid * 16 + 4096) >> 1;

    float st[4], kk[4], c0[4];
    if (PASS == 0) {
#pragma unroll
        for (int r = 0; r < 4; ++r) st[r] = -INFINITY;   // max dot
    } else {
#pragma unroll
        for (int r = 0; r < 4; ++r) {
            float dm = __uint_as_float(dmin_u[row0 + r]);
            kk[r] = 1.0f / (SIGMA * (dm + EPS_MIN));
            c0[r] = dm * kk[r];
            st[r] = 0.0f;
        }
    }

    // Prologue: stage 0
    {
        short8 v0 = yv[tid], v1 = yv[tid + 256];
        *(short8*)&lds[0][w0] = v0;
        *(short8*)&lds[0][w1] = v1;
    }
    __syncthreads();

    for (int s = 0; s < NS; ++s) {
        int cur = s & 1;
        short8 n0, n1;
        if (s + 1 < NS) {                          // issue-early (T14)
            n0 = yv[(s + 1) * 512 + tid];
            n1 = yv[(s + 1) * 512 + 256 + tid];
        }
#pragma unroll
        for (int t4 = 0; t4 < 4; ++t4) {
            int r    = t4 * 16 + lrow;             // y row within stage
            int base = r * 128;
            const char* lb = (const char*)&lds[cur][0];
            short8 b0 = *(const short8*)(lb + base + (((kblk * 16))      ^ ((r & 7) << 4)));
            short8 b1 = *(const short8*)(lb + base + (((64 + kblk * 16)) ^ ((r & 7) << 4)));
            floatx4 acc = {0.0f, 0.0f, 0.0f, 0.0f};
            acc = __builtin_amdgcn_mfma_f32_16x16x32_bf16(a0, b0, acc, 0, 0, 0);
            acc = __builtin_amdgcn_mfma_f32_16x16x32_bf16(a1, b1, acc, 0, 0, 0);
#pragma unroll
            for (int r4 = 0; r4 < 4; ++r4) {
                if (PASS == 0) {
                    st[r4] = fmaxf(st[r4], acc[r4]);
                } else {
                    float d2 = fmaf(-2.0f, acc[r4], 2.0f);
                    float d  = sqrtf(fmaxf(d2, 0.0f));
                    st[r4] += __expf(fmaf(-kk[r4], d, c0[r4]));  // arg <= 0
                }
            }
        }
        if (s + 1 < NS) {                          // write-late (T14)
            *(short8*)&lds[cur ^ 1][w0] = n0;
            *(short8*)&lds[cur ^ 1][w1] = n1;
        }
        __syncthreads();
    }

    // Reduce across the 16 lanes holding this row-group's columns.
#pragma unroll
    for (int off = 1; off < 16; off <<= 1) {
#pragma unroll
        for (int r = 0; r < 4; ++r) {
            float o = __shfl_xor(st[r], off);
            st[r] = (PASS == 0) ? fmaxf(st[r], o) : (st[r] + o);
        }
    }
    if (lrow == 0) {
#pragma unroll
        for (int r = 0; r < 4; ++r) {
            if (PASS == 0) {
                float d2 = fmaf(-2.0f, st[r], 2.0f);       // min d^2
                float d  = sqrtf(fmaxf(d2, 0.0f));
                atomicMin(&dmin_u[row0 + r], __float_as_uint(d)); // vals >= 0
            } else {
                atomicAdd(&S[row0 + r], st[r]);
            }
        }
    }
}

// ---------------------------------------------------------------------------
// loss = -log( mean(1/S + EPS_MIN) )
__global__ __launch_bounds__(256) void final_kernel(const float* __restrict__ S,
                                                    float* __restrict__ out) {
    const float4* S4 = (const float4*)S;
    float acc = 0.0f;
    for (int i = threadIdx.x; i < ROWS / 4; i += 256) {
        float4 v = S4[i];
        acc += __builtin_amdgcn_rcpf(v.x) + __builtin_amdgcn_rcpf(v.y) +
               __builtin_amdgcn_rcpf(v.z) + __builtin_amdgcn_rcpf(v.w) +
               4.0f * EPS_MIN;
    }
#pragma unroll
    for (int off = 32; off > 0; off >>= 1)
        acc += __shfl_down(acc, off);
    __shared__ float part[4];
    if ((threadIdx.x & 63) == 0) part[threadIdx.x >> 6] = acc;
    __syncthreads();
    if (threadIdx.x == 0) {
        float t = part[0] + part[1] + part[2] + part[3];
        out[0] = -logf(t / (float)ROWS);
    }
}

// ---------------------------------------------------------------------------
extern "C" void kernel_launch(void* const* d_in, const int* in_sizes, int n_in,
                              void* d_out, int out_size, void* d_ws, size_t ws_size,
                              hipStream_t stream) {
    const float* x = (const float*)d_in[0];
    const float* y = (const float*)d_in[1];
    float* out = (float*)d_out;

    char* ws = (char*)d_ws;
    size_t nrm_bytes = (size_t)ROWS * C_ * sizeof(ushort);   // 2 MB each
    ushort*   xn     = (ushort*)(ws);
    ushort*   yn     = (ushort*)(ws + nrm_bytes);
    unsigned* dmin_u = (unsigned*)(ws + 2 * nrm_bytes);
    float*    S      = (float*)(ws + 2 * nrm_bytes + (size_t)ROWS * sizeof(unsigned));

    hipLaunchKernelGGL(nrm_kernel, dim3(2 * ROWS / 256), dim3(256), 0, stream,
                       x, y, xn, yn, dmin_u, S);
    dim3 grid(HW / CC, HW / XR, B_);               // (8, 64, 4) = 2048 blocks
    hipLaunchKernelGGL(gemm_pass<0>, grid, dim3(256), 0, stream,
                       xn, yn, dmin_u, S);
    hipLaunchKernelGGL(gemm_pass<1>, grid, dim3(256), 0, stream,
                       xn, yn, dmin_u, S);
    hipLaunchKernelGGL(final_kernel, dim3(1), dim3(256), 0, stream, S, out);
}

// Round 5
// 101.996 us; speedup vs baseline: 6.2738x; 1.2072x over previous
//
#include <hip/hip_runtime.h>
#include <math.h>

// Problem constants (fixed by the reference): x,y are [4, 64, 64, 64] fp32.
constexpr int B_   = 4;
constexpr int C_   = 64;
constexpr int HW   = 4096;         // N = 64*64
constexpr int ROWS = B_ * HW;      // 16384

constexpr float SIGMA    = 0.1f;
constexpr float EPS_MIN  = 1e-5f;
constexpr float EPS_NORM = 1e-12f;
constexpr float LOG2E    = 1.44269504088896340736f;

// Block geometry: 4 waves, each owning 32 x-rows (block: XR=128 x-rows),
// sharing a CC=512-col y-chunk staged through LDS in SR=64-row dbuf stages.
constexpr int CC = 512;            // y-cols per block
constexpr int SR = 64;             // y-rows per LDS stage (8 KB)
constexpr int NS = CC / SR;        // 8 stages
constexpr int XR = 128;            // x-rows per block

using short8  = __attribute__((ext_vector_type(8))) short;   // 8 bf16
using floatx4 = __attribute__((ext_vector_type(4))) float;

__device__ inline ushort f2bf(float f) {           // RNE float->bf16
    unsigned u = __float_as_uint(f);
    unsigned r = u + 0x7FFFu + ((u >> 16) & 1u);
    return (ushort)(r >> 16);
}

// ---------------------------------------------------------------------------
// Normalize along C, write bf16 [B][N][C] point-major; also init dmin/S.
__global__ __launch_bounds__(256) void nrm_kernel(const float* __restrict__ x,
                                                  const float* __restrict__ y,
                                                  ushort* __restrict__ xn,
                                                  ushort* __restrict__ yn,
                                                  unsigned* __restrict__ dmin_u,
                                                  float* __restrict__ S) {
    int p = blockIdx.x * 256 + threadIdx.x;        // 0 .. 2*ROWS-1
    if (p < ROWS) { dmin_u[p] = 0x7F800000u; S[p] = 0.0f; }   // +inf, 0
    const float* src; ushort* dst; int q;
    if (p < ROWS) { src = x; dst = xn; q = p; }
    else          { src = y; dst = yn; q = p - ROWS; }
    int b = q >> 12;
    int n = q & (HW - 1);
    const float* base = src + ((size_t)b * C_) * HW + n;  // coalesced over n
    float v[C_];
    float ss = 0.0f;
#pragma unroll
    for (int c = 0; c < C_; ++c) {
        v[c] = base[(size_t)c * HW];
        ss = fmaf(v[c], v[c], ss);
    }
    float scale = 1.0f / fmaxf(sqrtf(ss), EPS_NORM);
    short8* o = (short8*)(dst + (size_t)q * C_);
#pragma unroll
    for (int c8 = 0; c8 < C_ / 8; ++c8) {
        short8 pk;
#pragma unroll
        for (int j = 0; j < 8; ++j) pk[j] = (short)f2bf(v[c8 * 8 + j] * scale);
        o[c8] = pk;
    }
}

// ---------------------------------------------------------------------------
// PASS 0: per-row max dot (min d monotone in dot) -> atomicMin of d bits.
// PASS 1: S[row] += sum_m exp2((dmin - d_m) * kk2),  kk2 = log2e/(sigma*(dmin+eps)).
// MFMA 16x16x32 C/D: col=lane&15 (y point), row=(lane>>4)*4+reg (x point).
// All LDS addressing in 16B-slot units on typed short8* so the compiler
// emits ds_read_b128 / ds_write_b128 (round-2 suspect: scalarized reads).
// Swizzle: slot' = slot ^ (row&7) on both write and read (involution).
template <int PASS>
__global__ __launch_bounds__(256, 4) void gemm_pass(const ushort* __restrict__ xn,
                                                    const ushort* __restrict__ yn,
                                                    unsigned* __restrict__ dmin_u,
                                                    float* __restrict__ S) {
    __shared__ short8 lds[2][SR * 8];              // 2 x 8 KB, 8 slots/row

    int tid  = threadIdx.x;
    int wid  = tid >> 6;
    int lane = tid & 63;
    int lrow = lane & 15;
    int kblk = lane >> 4;

    int b     = blockIdx.z;
    int nbase = blockIdx.y * XR + wid * 32;        // this wave's 32 x-rows
    int cbase = blockIdx.x * CC;

    const ushort* xb = xn + (size_t)(b * HW + nbase) * C_;
    const short8* yv = (const short8*)(yn + (size_t)(b * HW + cbase) * C_);

    // A fragments: tile0 = rows 0..15, tile1 = rows 16..31 (k 0..31 / 32..63)
    short8 a0 = *(const short8*)(xb + lrow * C_ + kblk * 8);
    short8 a1 = *(const short8*)(xb + lrow * C_ + 32 + kblk * 8);
    short8 a2 = *(const short8*)(xb + (16 + lrow) * C_ + kblk * 8);
    short8 a3 = *(const short8*)(xb + (16 + lrow) * C_ + 32 + kblk * 8);

    int row0 = b * HW + nbase + kblk * 4;          // + r (tile0), +16+r (tile1)

    // Staging slots (write side): element i of a stage -> row i>>3, slot i&7.
    int wrow = tid >> 3, wslot = tid & 7;
    int w0 = wrow * 8 + (wslot ^ (wrow & 7));
    int w1 = (wrow + 32) * 8 + (wslot ^ (wrow & 7));   // (row+32)&7 == row&7

    float st[8];                    // PASS0: max dot ; PASS1: exp2-sum
    float kk2[8], c02[8];
    if (PASS == 0) {
#pragma unroll
        for (int r = 0; r < 8; ++r) st[r] = -INFINITY;
    } else {
#pragma unroll
        for (int r = 0; r < 8; ++r) {
            int row = row0 + (r >> 2) * 16 + (r & 3);
            float dm = __uint_as_float(dmin_u[row]);
            kk2[r] = LOG2E / (SIGMA * (dm + EPS_MIN));
            c02[r] = dm * kk2[r];
            st[r]  = 0.0f;
        }
    }

    // Prologue: stage 0
    {
        short8 v0 = yv[tid], v1 = yv[tid + 256];
        lds[0][w0] = v0;
        lds[0][w1] = v1;
    }
    __syncthreads();

    for (int s = 0; s < NS; ++s) {
        int cur = s & 1;
        short8 n0, n1;
        if (s + 1 < NS) {                          // issue-early (T14)
            n0 = yv[(s + 1) * 512 + tid];
            n1 = yv[(s + 1) * 512 + 256 + tid];
        }
#pragma unroll
        for (int t4 = 0; t4 < 4; ++t4) {
            int r = t4 * 16 + lrow;                // y point within stage
            int p = r & 7;
            short8 y0 = lds[cur][r * 8 + (kblk ^ p)];         // k 0..31
            short8 y1 = lds[cur][r * 8 + ((kblk + 4) ^ p)];   // k 32..63
            floatx4 acc0 = {0.0f, 0.0f, 0.0f, 0.0f};
            floatx4 acc1 = {0.0f, 0.0f, 0.0f, 0.0f};
            acc0 = __builtin_amdgcn_mfma_f32_16x16x32_bf16(a0, y0, acc0, 0, 0, 0);
            acc0 = __builtin_amdgcn_mfma_f32_16x16x32_bf16(a1, y1, acc0, 0, 0, 0);
            acc1 = __builtin_amdgcn_mfma_f32_16x16x32_bf16(a2, y0, acc1, 0, 0, 0);
            acc1 = __builtin_amdgcn_mfma_f32_16x16x32_bf16(a3, y1, acc1, 0, 0, 0);
#pragma unroll
            for (int r4 = 0; r4 < 8; ++r4) {
                float a = (r4 < 4) ? acc0[r4 & 3] : acc1[r4 & 3];
                if (PASS == 0) {
                    st[r4] = fmaxf(st[r4], a);
                } else {
                    float d2 = fmaxf(fmaf(-2.0f, a, 2.0f), 0.0f);
                    float d  = __builtin_amdgcn_sqrtf(d2);
                    st[r4] += __builtin_amdgcn_exp2f(fmaf(-kk2[r4], d, c02[r4]));
                }
            }
        }
        if (s + 1 < NS) {                          // write-late (T14)
            lds[cur ^ 1][w0] = n0;
            lds[cur ^ 1][w1] = n1;
        }
        __syncthreads();
    }

    // Reduce across the 16 lanes holding this row-group's columns.
#pragma unroll
    for (int off = 1; off < 16; off <<= 1) {
#pragma unroll
        for (int r = 0; r < 8; ++r) {
            float o = __shfl_xor(st[r], off);
            st[r] = (PASS == 0) ? fmaxf(st[r], o) : (st[r] + o);
        }
    }
    if (lrow == 0) {
#pragma unroll
        for (int r = 0; r < 8; ++r) {
            int row = row0 + (r >> 2) * 16 + (r & 3);
            if (PASS == 0) {
                float d2 = fmaxf(fmaf(-2.0f, st[r], 2.0f), 0.0f);  // min d^2
                float d  = sqrtf(d2);
                atomicMin(&dmin_u[row], __float_as_uint(d));  // vals >= 0
            } else {
                atomicAdd(&S[row], st[r]);
            }
        }
    }
}

// ---------------------------------------------------------------------------
// loss = -log( mean(1/S + EPS_MIN) )
__global__ __launch_bounds__(256) void final_kernel(const float* __restrict__ S,
                                                    float* __restrict__ out) {
    const float4* S4 = (const float4*)S;
    float acc = 0.0f;
    for (int i = threadIdx.x; i < ROWS / 4; i += 256) {
        float4 v = S4[i];
        acc += __builtin_amdgcn_rcpf(v.x) + __builtin_amdgcn_rcpf(v.y) +
               __builtin_amdgcn_rcpf(v.z) + __builtin_amdgcn_rcpf(v.w) +
               4.0f * EPS_MIN;
    }
#pragma unroll
    for (int off = 32; off > 0; off >>= 1)
        acc += __shfl_down(acc, off);
    __shared__ float part[4];
    if ((threadIdx.x & 63) == 0) part[threadIdx.x >> 6] = acc;
    __syncthreads();
    if (threadIdx.x == 0) {
        float t = part[0] + part[1] + part[2] + part[3];
        out[0] = -logf(t / (float)ROWS);
    }
}

// ---------------------------------------------------------------------------
extern "C" void kernel_launch(void* const* d_in, const int* in_sizes, int n_in,
                              void* d_out, int out_size, void* d_ws, size_t ws_size,
                              hipStream_t stream) {
    const float* x = (const float*)d_in[0];
    const float* y = (const float*)d_in[1];
    float* out = (float*)d_out;

    char* ws = (char*)d_ws;
    size_t nrm_bytes = (size_t)ROWS * C_ * sizeof(ushort);   // 2 MB each
    ushort*   xn     = (ushort*)(ws);
    ushort*   yn     = (ushort*)(ws + nrm_bytes);
    unsigned* dmin_u = (unsigned*)(ws + 2 * nrm_bytes);
    float*    S      = (float*)(ws + 2 * nrm_bytes + (size_t)ROWS * sizeof(unsigned));

    hipLaunchKernelGGL(nrm_kernel, dim3(2 * ROWS / 256), dim3(256), 0, stream,
                       x, y, xn, yn, dmin_u, S);
    dim3 grid(HW / CC, HW / XR, B_);               // (8, 32, 4) = 1024 blocks
    hipLaunchKernelGGL(gemm_pass<0>, grid, dim3(256), 0, stream,
                       xn, yn, dmin_u, S);
    hipLaunchKernelGGL(gemm_pass<1>, grid, dim3(256), 0, stream,
                       xn, yn, dmin_u, S);
    hipLaunchKernelGGL(final_kernel, dim3(1), dim3(256), 0, stream, S, out);
}

// Round 6
// 100.530 us; speedup vs baseline: 6.3653x; 1.0146x over previous
//
#include <hip/hip_runtime.h>
#include <math.h>

// Problem constants (fixed by the reference): x,y are [4, 64, 64, 64] fp32.
constexpr int B_   = 4;
constexpr int C_   = 64;
constexpr int HW   = 4096;         // N = 64*64
constexpr int ROWS = B_ * HW;      // 16384

constexpr float SIGMA    = 0.1f;
constexpr float EPS_MIN  = 1e-5f;
constexpr float EPS_NORM = 1e-12f;
constexpr float LOG2E    = 1.44269504088896340736f;

// Block geometry: 4 waves x 64 x-rows = 256 x-rows per block, sharing a
// CC=512-col y-chunk staged through LDS in SR=64-row double-buffered stages.
constexpr int CC = 512;            // y-cols per block
constexpr int SR = 64;             // y-rows per LDS stage (8 KB)
constexpr int NS = CC / SR;        // 8 stages
constexpr int XR = 256;            // x-rows per block (4 waves x 64)

using short8  = __attribute__((ext_vector_type(8))) short;   // 8 bf16
using floatx4 = __attribute__((ext_vector_type(4))) float;

__device__ inline ushort f2bf(float f) {           // RNE float->bf16
    unsigned u = __float_as_uint(f);
    unsigned r = u + 0x7FFFu + ((u >> 16) & 1u);
    return (ushort)(r >> 16);
}

// ---------------------------------------------------------------------------
// Normalize along C, write bf16 [B][N][C] point-major; also init dmin/S.
__global__ __launch_bounds__(256) void nrm_kernel(const float* __restrict__ x,
                                                  const float* __restrict__ y,
                                                  ushort* __restrict__ xn,
                                                  ushort* __restrict__ yn,
                                                  unsigned* __restrict__ dmin_u,
                                                  float* __restrict__ S) {
    int p = blockIdx.x * 256 + threadIdx.x;        // 0 .. 2*ROWS-1
    if (p < ROWS) { dmin_u[p] = 0x7F800000u; S[p] = 0.0f; }   // +inf, 0
    const float* src; ushort* dst; int q;
    if (p < ROWS) { src = x; dst = xn; q = p; }
    else          { src = y; dst = yn; q = p - ROWS; }
    int b = q >> 12;
    int n = q & (HW - 1);
    const float* base = src + ((size_t)b * C_) * HW + n;  // coalesced over n
    float v[C_];
    float ss = 0.0f;
#pragma unroll
    for (int c = 0; c < C_; ++c) {
        v[c] = base[(size_t)c * HW];
        ss = fmaf(v[c], v[c], ss);
    }
    float scale = 1.0f / fmaxf(sqrtf(ss), EPS_NORM);
    short8* o = (short8*)(dst + (size_t)q * C_);
#pragma unroll
    for (int c8 = 0; c8 < C_ / 8; ++c8) {
        short8 pk;
#pragma unroll
        for (int j = 0; j < 8; ++j) pk[j] = (short)f2bf(v[c8 * 8 + j] * scale);
        o[c8] = pk;
    }
}

// ---------------------------------------------------------------------------
// SWAPPED-OPERAND GEMM: mfma(A=y, B=x) -> D col = x point (lane&15),
// D row = y point ((lane>>4)*4+reg).  Each lane accumulates its x-col's
// reduction over y IN REGISTER (st[xt]); cross-lane combine is 2 shfls at
// kernel end.  Final scalar is invariant to any consistent point
// permutation, and k-permutations cancel between identically-loaded frags.
// PASS 0: per-x-row max dot -> dmin via atomicMin on float bits.
// PASS 1: S[row] += sum_m exp2((dmin-d)*kk2), kk2 = log2e/(sigma*(dmin+eps)).
template <int PASS>
__global__ __launch_bounds__(256, 2) void gemm_pass(const ushort* __restrict__ xn,
                                                    const ushort* __restrict__ yn,
                                                    unsigned* __restrict__ dmin_u,
                                                    float* __restrict__ S) {
    __shared__ short8 lds[2][SR * 8];              // 2 x 8 KB, 8 slots/row

    int tid  = threadIdx.x;
    int wid  = tid >> 6;
    int lane = tid & 63;
    int lrow = lane & 15;                          // x-col within tile
    int kgrp = lane >> 4;                          // k-group 0..3

    int b     = blockIdx.z;
    int nbase = blockIdx.y * XR + wid * 64;        // this wave's 64 x-rows
    int cbase = blockIdx.x * CC;

    const ushort* xb = xn + (size_t)(b * HW + nbase) * C_;
    const short8* yv = (const short8*)(yn + (size_t)(b * HW + cbase) * C_);

    // x B-fragments: 4 tiles x (k0..31, k32..63), pinned in registers.
    short8 xb0[4], xb1[4];
#pragma unroll
    for (int xt = 0; xt < 4; ++xt) {
        xb0[xt] = *(const short8*)(xb + (xt * 16 + lrow) * C_ + kgrp * 8);
        xb1[xt] = *(const short8*)(xb + (xt * 16 + lrow) * C_ + 32 + kgrp * 8);
    }

    // This lane's 4 output x-rows (one per x-tile).
    int row0 = b * HW + nbase + lrow;              // + xt*16

    // Staging slots (write side): element i of a stage -> row i>>3, slot i&7.
    int wrow = tid >> 3, wslot = tid & 7;
    int w0 = wrow * 8 + (wslot ^ (wrow & 7));
    int w1 = (wrow + 32) * 8 + (wslot ^ (wrow & 7));   // (row+32)&7 == row&7

    float st[4];                    // PASS0: max dot ; PASS1: exp2-sum
    float kk2[4], c02[4];
    if (PASS == 0) {
#pragma unroll
        for (int xt = 0; xt < 4; ++xt) st[xt] = -INFINITY;
    } else {
#pragma unroll
        for (int xt = 0; xt < 4; ++xt) {
            float dm = __uint_as_float(dmin_u[row0 + xt * 16]);
            kk2[xt] = LOG2E / (SIGMA * (dm + EPS_MIN));
            c02[xt] = dm * kk2[xt];
            st[xt]  = 0.0f;
        }
    }

    // Prologue: stage 0
    {
        short8 v0 = yv[tid], v1 = yv[tid + 256];
        lds[0][w0] = v0;
        lds[0][w1] = v1;
    }
    __syncthreads();

    for (int s = 0; s < NS; ++s) {
        int cur = s & 1;
        short8 n0, n1;
        if (s + 1 < NS) {                          // issue-early (T14)
            n0 = yv[(s + 1) * 512 + tid];
            n1 = yv[(s + 1) * 512 + 256 + tid];
        }
#pragma unroll
        for (int yt = 0; yt < 4; ++yt) {
            int p = yt * 16 + lrow;                // y point (A row)
            int q = p & 7;
            short8 ya0 = lds[cur][p * 8 + (kgrp ^ q)];         // k 0..31
            short8 ya1 = lds[cur][p * 8 + ((kgrp + 4) ^ q)];   // k 32..63
#pragma unroll
            for (int xt = 0; xt < 4; ++xt) {
                floatx4 acc = {0.0f, 0.0f, 0.0f, 0.0f};
                acc = __builtin_amdgcn_mfma_f32_16x16x32_bf16(ya0, xb0[xt], acc, 0, 0, 0);
                acc = __builtin_amdgcn_mfma_f32_16x16x32_bf16(ya1, xb1[xt], acc, 0, 0, 0);
                if (PASS == 0) {
                    st[xt] = fmaxf(st[xt],
                             fmaxf(fmaxf(acc[0], acc[1]), fmaxf(acc[2], acc[3])));
                } else {
#pragma unroll
                    for (int r = 0; r < 4; ++r) {
                        float d2 = fmaxf(fmaf(-2.0f, acc[r], 2.0f), 0.0f);
                        float d  = __builtin_amdgcn_sqrtf(d2);
                        st[xt] += __builtin_amdgcn_exp2f(fmaf(-kk2[xt], d, c02[xt]));
                    }
                }
            }
        }
        if (s + 1 < NS) {                          // write-late (T14)
            lds[cur ^ 1][w0] = n0;
            lds[cur ^ 1][w1] = n1;
        }
        __syncthreads();
    }

    // Combine the 4 k-groups (lanes sharing lrow hold disjoint y rows).
#pragma unroll
    for (int off = 16; off < 64; off <<= 1) {
#pragma unroll
        for (int xt = 0; xt < 4; ++xt) {
            float o = __shfl_xor(st[xt], off);
            st[xt] = (PASS == 0) ? fmaxf(st[xt], o) : (st[xt] + o);
        }
    }
    if (kgrp == 0) {                               // lanes 0..15
#pragma unroll
        for (int xt = 0; xt < 4; ++xt) {
            int row = row0 + xt * 16;
            if (PASS == 0) {
                float d2 = fmaxf(fmaf(-2.0f, st[xt], 2.0f), 0.0f);  // min d^2
                float d  = sqrtf(d2);
                atomicMin(&dmin_u[row], __float_as_uint(d));  // vals >= 0
            } else {
                atomicAdd(&S[row], st[xt]);
            }
        }
    }
}

// ---------------------------------------------------------------------------
// loss = -log( mean(1/S + EPS_MIN) )
__global__ __launch_bounds__(256) void final_kernel(const float* __restrict__ S,
                                                    float* __restrict__ out) {
    const float4* S4 = (const float4*)S;
    float acc = 0.0f;
    for (int i = threadIdx.x; i < ROWS / 4; i += 256) {
        float4 v = S4[i];
        acc += __builtin_amdgcn_rcpf(v.x) + __builtin_amdgcn_rcpf(v.y) +
               __builtin_amdgcn_rcpf(v.z) + __builtin_amdgcn_rcpf(v.w) +
               4.0f * EPS_MIN;
    }
#pragma unroll
    for (int off = 32; off > 0; off >>= 1)
        acc += __shfl_down(acc, off);
    __shared__ float part[4];
    if ((threadIdx.x & 63) == 0) part[threadIdx.x >> 6] = acc;
    __syncthreads();
    if (threadIdx.x == 0) {
        float t = part[0] + part[1] + part[2] + part[3];
        out[0] = -logf(t / (float)ROWS);
    }
}

// ---------------------------------------------------------------------------
extern "C" void kernel_launch(void* const* d_in, const int* in_sizes, int n_in,
                              void* d_out, int out_size, void* d_ws, size_t ws_size,
                              hipStream_t stream) {
    const float* x = (const float*)d_in[0];
    const float* y = (const float*)d_in[1];
    float* out = (float*)d_out;

    char* ws = (char*)d_ws;
    size_t nrm_bytes = (size_t)ROWS * C_ * sizeof(ushort);   // 2 MB each
    ushort*   xn     = (ushort*)(ws);
    ushort*   yn     = (ushort*)(ws + nrm_bytes);
    unsigned* dmin_u = (unsigned*)(ws + 2 * nrm_bytes);
    float*    S      = (float*)(ws + 2 * nrm_bytes + (size_t)ROWS * sizeof(unsigned));

    hipLaunchKernelGGL(nrm_kernel, dim3(2 * ROWS / 256), dim3(256), 0, stream,
                       x, y, xn, yn, dmin_u, S);
    dim3 grid(HW / CC, HW / XR, B_);               // (8, 16, 4) = 512 blocks
    hipLaunchKernelGGL(gemm_pass<0>, grid, dim3(256), 0, stream,
                       xn, yn, dmin_u, S);
    hipLaunchKernelGGL(gemm_pass<1>, grid, dim3(256), 0, stream,
                       xn, yn, dmin_u, S);
    hipLaunchKernelGGL(final_kernel, dim3(1), dim3(256), 0, stream, S, out);
}